// Round 1
// baseline (248.868 us; speedup 1.0000x reference)
//
#include <hip/hip_runtime.h>

// ModulatedConv2d (StyleGAN2): B=8, Cin=Cout=512, k=3, H=W=64.
// Decomposition:
//   s[b,c]     = style @ (mod_weight/sqrt(512))^T + bias          (fp32)
//   scale[b,o] = conv_scale * rsqrt(conv_scale^2 * sum_c wsq[o,c]*s^2 + eps)
//   out[b,o,p] = scale[b,o] * sum_{c,k} w[o,c,k] * (s[b,c]*x[b,c,p'])
// GEMM operands in bf16 (threshold 0.109 allows it), accum fp32 via MFMA.

#define BATCH 8
#define CH 512

typedef __bf16 bf16x8 __attribute__((ext_vector_type(8)));
typedef float f32x16 __attribute__((ext_vector_type(16)));

__device__ __forceinline__ unsigned short f2bf(float f) {
  union { float f; unsigned int u; } v; v.f = f;
  unsigned int u = v.u;
  return (unsigned short)((u + 0x7fffu + ((u >> 16) & 1u)) >> 16);
}

// s[b,c] = sum_d style[b,d]*mw[c,d]*(1/sqrt(512)) + mb[c]; also zero the zeropage
__global__ void k_mod(const float* __restrict__ style, const float* __restrict__ mw,
                      const float* __restrict__ mb, float* __restrict__ s,
                      float* __restrict__ zp) {
  int t = blockIdx.x * 256 + threadIdx.x;   // 4096
  if (blockIdx.x == 0) zp[threadIdx.x] = 0.f;  // 1KB zero page
  int b = t >> 9, c = t & 511;
  float acc = 0.f;
  for (int d = 0; d < 512; ++d) acc += style[b * 512 + d] * mw[c * 512 + d];
  s[t] = acc * 0.04419417382415922f + mb[c];  // 1/sqrt(512)
}

// wsq[o,c] = sum_k w^2 ; wbf[k][o][c] = bf16(w[o][c][k])
__global__ void k_wprep(const float* __restrict__ w, float* __restrict__ wsq,
                        unsigned short* __restrict__ wbf) {
  int t = blockIdx.x * 256 + threadIdx.x;   // 262144
  int o = t >> 9, c = t & 511;
  const float* wp = w + (size_t)(o * 512 + c) * 9;
  float q = 0.f;
#pragma unroll
  for (int k = 0; k < 9; ++k) {
    float v = wp[k];
    q += v * v;
    wbf[((size_t)k * 512 + o) * 512 + c] = f2bf(v);
  }
  wsq[t] = q;
}

// scale[b,o] = cs * rsqrt(cs^2 * sum_c wsq[o,c]*s[b,c]^2 + 1e-8)
__global__ void k_scale(const float* __restrict__ wsq, const float* __restrict__ s,
                        float* __restrict__ scale) {
  int t = blockIdx.x * 256 + threadIdx.x;   // 4096
  int b = t >> 9, o = t & 511;
  float acc = 0.f;
  for (int c = 0; c < 512; ++c) {
    float sv = s[b * 512 + c];
    acc += wsq[o * 512 + c] * sv * sv;
  }
  const float cs = 0.014731391274719739f;   // 1/sqrt(4608)
  scale[t] = cs * rsqrtf(cs * cs * acc + 1e-8f);
}

// xt[b][y][x][c] = bf16(s[b,c] * x[b,c,y,x])   (channel-contiguous for MFMA K)
__global__ void k_xt(const float* __restrict__ x, const float* __restrict__ s,
                     unsigned short* __restrict__ xt) {
  int bid = blockIdx.x;                     // 8*16*64 = 8192
  int b = bid >> 10, cc = (bid >> 6) & 15, y = bid & 63;
  int t = threadIdx.x;
  int ci = t >> 3, xg = t & 7;
  int c = cc * 32 + ci;
  const float* xp = x + (((size_t)(b * 512 + c) * 64 + y) * 64 + xg * 8);
  float sv = s[b * 512 + c];
  float4 v0 = *(const float4*)xp;
  float4 v1 = *(const float4*)(xp + 4);
  unsigned short r[8];
  r[0] = f2bf(v0.x * sv); r[1] = f2bf(v0.y * sv);
  r[2] = f2bf(v0.z * sv); r[3] = f2bf(v0.w * sv);
  r[4] = f2bf(v1.x * sv); r[5] = f2bf(v1.y * sv);
  r[6] = f2bf(v1.z * sv); r[7] = f2bf(v1.w * sv);
  size_t base = ((size_t)(b * 64 + y) * 64) * 512 + c;
#pragma unroll
  for (int j = 0; j < 8; ++j) xt[base + (size_t)(xg * 8 + j) * 512] = r[j];
}

// XOR swizzle on region-local bf16-element offset (32 elems = 64B per row).
// Applied identically on the read side and (inverted, = same XOR) on the
// global source during staging -> correctness-safe involution, spreads
// 64B-stride rows across 8x16B bank slots.
__device__ __forceinline__ int swz(int f) {
  int row = f >> 5;
  int byt = (f & 31) << 1;
  byt ^= (row & 3) << 4;
  return (row << 5) + (byt >> 1);
}

#define XELEMS 12672          // 6 rows * 66 xi * 32 c
#define WOFFU  12800          // ushort offset of W region (25600 B, 64B-row aligned)
#define NXISS  25             // ceil(25344/1024)
#define NWISS  36             // 36864/1024

__global__ __launch_bounds__(256, 2) void k_conv(
    const unsigned short* __restrict__ xt, const unsigned short* __restrict__ wbf,
    const float* __restrict__ scale, const float* __restrict__ zp,
    float* __restrict__ out) {
  // LDS: X tile [6 rows][66 xi][32 c] (+pad) then W tile [9 tap][64 o][32 c]
  __shared__ __align__(16) unsigned short lds[12800 + 18432];  // 62464 B
  int bid = blockIdx.x;                    // 1024 = 8 ob * 8 b * 16 yg
  int ob = bid >> 7, b = (bid >> 4) & 7, yg = bid & 15;
  int y0 = yg * 4;
  int tid = threadIdx.x;
  int wy = tid >> 6, lane = tid & 63;
  int ln31 = lane & 31, hi8 = (lane >> 5) * 8;

  f32x16 acc00 = {0,0,0,0,0,0,0,0,0,0,0,0,0,0,0,0};
  f32x16 acc01 = {0,0,0,0,0,0,0,0,0,0,0,0,0,0,0,0};
  f32x16 acc10 = {0,0,0,0,0,0,0,0,0,0,0,0,0,0,0,0};
  f32x16 acc11 = {0,0,0,0,0,0,0,0,0,0,0,0,0,0,0,0};

  const unsigned short* xbase = xt + (size_t)b * 64 * 64 * 512;

  for (int cc = 0; cc < 16; ++cc) {
    __syncthreads();
    // ---- stage X (25 issues) + W (36 issues), distributed across 4 waves ----
    for (int is = wy; is < NXISS + NWISS; is += 4) {
      if (is < NXISS) {
        int p = is * 1024 + lane * 16;        // dest byte in X region (linear)
        int rowb = p >> 6;
        int slot = (p >> 4) & 3;
        int e0 = rowb * 32 + (slot ^ (rowb & 3)) * 8;  // inverse-swizzled source elem
        const unsigned short* src;
        if (e0 < XELEMS) {
          int r = e0 / 2112;
          int rem = e0 - r * 2112;
          int xi = rem >> 5, c0 = rem & 31;
          int yy = y0 + r - 1, xx = xi - 1;
          src = (yy >= 0 && yy < 64 && xx >= 0 && xx < 64)
                    ? xbase + (((size_t)yy * 64 + xx) * 512 + cc * 32 + c0)
                    : (const unsigned short*)zp;
        } else {
          src = (const unsigned short*)zp;
        }
        __builtin_amdgcn_global_load_lds(
            (const __attribute__((address_space(1))) void*)src,
            (__attribute__((address_space(3))) void*)&lds[is * 512], 16, 0, 0);
      } else {
        int j = is - NXISS;
        int p = j * 1024 + lane * 16;
        int rowb = p >> 6;
        int slot = (p >> 4) & 3;
        int e0 = rowb * 32 + (slot ^ (rowb & 3)) * 8;
        int kidx = e0 >> 11;
        int rem = e0 & 2047;
        int o = rem >> 5, c0 = rem & 31;
        const unsigned short* src =
            wbf + (((size_t)kidx * 512 + ob * 64 + o) * 512 + cc * 32 + c0);
        __builtin_amdgcn_global_load_lds(
            (const __attribute__((address_space(1))) void*)src,
            (__attribute__((address_space(3))) void*)&lds[WOFFU + j * 512], 16, 0, 0);
      }
    }
    __syncthreads();
    // ---- compute: 9 taps x 2 k-steps x (2 A + 2 B reads, 4 MFMA) ----
#pragma unroll
    for (int kidx = 0; kidx < 9; ++kidx) {
      int ky = kidx / 3, kx = kidx % 3;
      int r = wy + ky;
#pragma unroll
      for (int ks = 0; ks < 2; ++ks) {
        int fA0 = ((kidx * 64 + ln31) << 5) + ks * 16 + hi8;
        int fA1 = fA0 + (32 << 5);
        int fB0 = ((r * 66 + ln31 + kx) << 5) + ks * 16 + hi8;
        int fB1 = fB0 + (32 << 5);
        bf16x8 a0 = *(const bf16x8*)&lds[WOFFU + swz(fA0)];
        bf16x8 a1 = *(const bf16x8*)&lds[WOFFU + swz(fA1)];
        bf16x8 b0 = *(const bf16x8*)&lds[swz(fB0)];
        bf16x8 b1 = *(const bf16x8*)&lds[swz(fB1)];
        acc00 = __builtin_amdgcn_mfma_f32_32x32x16_bf16(a0, b0, acc00, 0, 0, 0);
        acc01 = __builtin_amdgcn_mfma_f32_32x32x16_bf16(a0, b1, acc01, 0, 0, 0);
        acc10 = __builtin_amdgcn_mfma_f32_32x32x16_bf16(a1, b0, acc10, 0, 0, 0);
        acc11 = __builtin_amdgcn_mfma_f32_32x32x16_bf16(a1, b1, acc11, 0, 0, 0);
      }
    }
  }

  // ---- epilogue: C/D layout col=lane&31, row=(reg&3)+8*(reg>>2)+4*(lane>>5) ----
  int y = y0 + wy;
  int obase = ob * 64;
  float* op = out + ((size_t)(b * 512 + obase) * 64 + y) * 64;
  int hi4 = (lane >> 5) * 4;
#pragma unroll
  for (int mi = 0; mi < 2; ++mi) {
    const f32x16& A0 = mi ? acc10 : acc00;
    const f32x16& A1 = mi ? acc11 : acc01;
#pragma unroll
    for (int reg = 0; reg < 16; ++reg) {
      int row = (reg & 3) + 8 * (reg >> 2) + hi4;
      int o = mi * 32 + row;
      float sc = scale[b * 512 + obase + o];
      op[(size_t)o * 4096 + ln31] = A0[reg] * sc;
      op[(size_t)o * 4096 + 32 + ln31] = A1[reg] * sc;
    }
  }
}

extern "C" void kernel_launch(void* const* d_in, const int* in_sizes, int n_in,
                              void* d_out, int out_size, void* d_ws, size_t ws_size,
                              hipStream_t stream) {
  const float* x     = (const float*)d_in[0];  // [8,512,64,64]
  const float* style = (const float*)d_in[1];  // [8,512]
  const float* w     = (const float*)d_in[2];  // [1,512,512,3,3]
  const float* mw    = (const float*)d_in[3];  // [512,512]
  const float* mb    = (const float*)d_in[4];  // [512]
  float* out = (float*)d_out;

  char* ws = (char*)d_ws;
  float* zp    = (float*)ws;                       // 1 KB zeros
  float* s     = (float*)(ws + 1024);              // 16 KB
  float* scale = (float*)(ws + 17408);             // 16 KB
  float* wsq   = (float*)(ws + 33792);             // 1 MB
  unsigned short* wbf = (unsigned short*)(ws + 1082368);   // 4.72 MB  [9][512][512]
  unsigned short* xt  = (unsigned short*)(ws + 5800960);   // 33.5 MB  [8][64][64][512]

  k_mod  <<<16,   256, 0, stream>>>(style, mw, mb, s, zp);
  k_wprep<<<1024, 256, 0, stream>>>(w, wsq, wbf);
  k_scale<<<16,   256, 0, stream>>>(wsq, s, scale);
  k_xt   <<<8192, 256, 0, stream>>>(x, s, xt);
  k_conv <<<1024, 256, 0, stream>>>(xt, wbf, scale, zp, out);
}